// Round 19
// baseline (49.849 us; speedup 1.0000x reference)
//
#include <hip/hip_runtime.h>

// SSIM v31: v29 main loop VERBATIM (33.3us best: gload_lds quad-buffer,
// counted vmcnt(6), XCD-locality swizzle, cvt_pk RNE packing) fused into
// a SINGLE kernel. v30 (LDS pre-read at depth-1) regressed 33.3->35.7 ->
// v29's schedule is the loop optimum; the remaining reducible term is
// dispatch overhead: 3 serial launches (setup/main/reduce) = ~4-6us of
// the 33.3us wall. v31: (1) weights computed per-thread in-kernel
// (pk_bf16 software RNE -> bit-identical words); (2) final reduction via
// device-scope double atomicAdd + last-block-finishes (threadfence +
// counter); accumulator zeroed by a 16B hipMemsetAsync in kernel_launch
// (graph-capture-safe). Main math byte-identical; 768 partials sum in
// double (rel err <1e-12) -> absmax stays exactly 0.0078125.

typedef __attribute__((ext_vector_type(8))) short bf16x8;
typedef __attribute__((ext_vector_type(4))) float f32x4;
typedef __attribute__((ext_vector_type(2))) float f32x2;
typedef __attribute__((ext_vector_type(2))) __bf16 bfx2;

constexpr int TX   = 64;             // block out-cols (4 waves x 16)
constexpr int BY   = 256;            // block out-rows
constexpr int IMW  = 512;
constexpr int IMH  = 512;
constexpr int NPL  = 48;
constexpr int GX   = IMW / TX;       // 8
constexpr int GYB  = IMH / BY;       // 2
constexpr int NBLK = GX * GYB * NPL; // 768
constexpr int NCH  = BY / 16;        // 16; chunks 0..16
constexpr int CB   = 12288;          // bytes per chunk buffer (768 float4)
constexpr float C1c = 0.01f * 0.01f;
constexpr float C2c = 0.03f * 0.03f;

union frag {
    bf16x8 f;
    unsigned int u[4];
    uint4 q;
};

// RNE f32->bf16 pair pack, software (weight init; bit-identical to HW RNE).
__device__ __forceinline__ unsigned int pk_bf16(float lo, float hi) {
    unsigned int a = __float_as_uint(lo);
    unsigned int b = __float_as_uint(hi);
    a += 0x7FFFu + ((a >> 16) & 1u);
    b += 0x7FFFu + ((b >> 16) & 1u);
    return (b & 0xFFFF0000u) | (a >> 16);
}

// HW RNE pair pack: vector fptrunc -> v_cvt_pk_bf16_f32 (1 VALU op).
__device__ __forceinline__ unsigned int pk_rne(float lo, float hi) {
    f32x2 v; v.x = lo; v.y = hi;
    bfx2 b = __builtin_convertvector(v, bfx2);
    return *reinterpret_cast<unsigned int*>(&b);
}

// Normalized 11-tap Gaussian (sigma=1.5); wt[d] for d in [0,11), else 0.
__device__ __forceinline__ float wsel(int d) {
    float w = 0.f;
    w = (d == 0 || d == 10) ? 0.00102838f : w;
    w = (d == 1 || d == 9)  ? 0.00759876f : w;
    w = (d == 2 || d == 8)  ? 0.03600077f : w;
    w = (d == 3 || d == 7)  ? 0.10936082f : w;
    w = (d == 4 || d == 6)  ? 0.21300553f : w;
    w = (d == 5)            ? 0.26601171f : w;
    return w;
}

// H-pass for one chunk from LDS: read 2 f4/img (= v12's 8 fragment floats),
// zero-predicate, pack (RNE cvt_pk), 5 MFMAs -> packed D (uint2 per plane).
template<int OFF>
__device__ __forceinline__ void cstep(const char* lds, int ro0, int ro1, bool ok,
                                      const frag& whf,
                                      uint2* __restrict__ D)
{
    float4 ra0 = *reinterpret_cast<const float4*>(lds + OFF + ro0);
    float4 ra1 = *reinterpret_cast<const float4*>(lds + OFF + ro1);
    float4 rb0 = *reinterpret_cast<const float4*>(lds + OFF + CB / 2 + ro0);
    float4 rb1 = *reinterpret_cast<const float4*>(lds + OFF + CB / 2 + ro1);
    const float4 zz = make_float4(0.f, 0.f, 0.f, 0.f);
    if (!ok) { ra0 = zz; ra1 = zz; rb0 = zz; rb1 = zz; }

    const f32x4 z = {0.f, 0.f, 0.f, 0.f};
    frag fa, fb, faa, fbb, fab;
    fa.u[0]  = pk_rne(ra0.x, ra0.y);               fb.u[0]  = pk_rne(rb0.x, rb0.y);
    faa.u[0] = pk_rne(ra0.x*ra0.x, ra0.y*ra0.y);
    fbb.u[0] = pk_rne(rb0.x*rb0.x, rb0.y*rb0.y);
    fab.u[0] = pk_rne(ra0.x*rb0.x, ra0.y*rb0.y);
    fa.u[1]  = pk_rne(ra0.z, ra0.w);               fb.u[1]  = pk_rne(rb0.z, rb0.w);
    faa.u[1] = pk_rne(ra0.z*ra0.z, ra0.w*ra0.w);
    fbb.u[1] = pk_rne(rb0.z*rb0.z, rb0.w*rb0.w);
    fab.u[1] = pk_rne(ra0.z*rb0.z, ra0.w*rb0.w);
    fa.u[2]  = pk_rne(ra1.x, ra1.y);               fb.u[2]  = pk_rne(rb1.x, rb1.y);
    faa.u[2] = pk_rne(ra1.x*ra1.x, ra1.y*ra1.y);
    fbb.u[2] = pk_rne(rb1.x*rb1.x, rb1.y*rb1.y);
    fab.u[2] = pk_rne(ra1.x*rb1.x, ra1.y*rb1.y);
    fa.u[3]  = pk_rne(ra1.z, ra1.w);               fb.u[3]  = pk_rne(rb1.z, rb1.w);
    faa.u[3] = pk_rne(ra1.z*ra1.z, ra1.w*ra1.w);
    fbb.u[3] = pk_rne(rb1.z*rb1.z, rb1.w*rb1.w);
    fab.u[3] = pk_rne(ra1.z*rb1.z, ra1.w*rb1.w);

    f32x4 d;
    d = __builtin_amdgcn_mfma_f32_16x16x32_bf16(fa.f,  whf.f, z, 0, 0, 0);
    D[0] = make_uint2(pk_rne(d[0], d[1]), pk_rne(d[2], d[3]));
    d = __builtin_amdgcn_mfma_f32_16x16x32_bf16(fb.f,  whf.f, z, 0, 0, 0);
    D[1] = make_uint2(pk_rne(d[0], d[1]), pk_rne(d[2], d[3]));
    d = __builtin_amdgcn_mfma_f32_16x16x32_bf16(faa.f, whf.f, z, 0, 0, 0);
    D[2] = make_uint2(pk_rne(d[0], d[1]), pk_rne(d[2], d[3]));
    d = __builtin_amdgcn_mfma_f32_16x16x32_bf16(fbb.f, whf.f, z, 0, 0, 0);
    D[3] = make_uint2(pk_rne(d[0], d[1]), pk_rne(d[2], d[3]));
    d = __builtin_amdgcn_mfma_f32_16x16x32_bf16(fab.f, whf.f, z, 0, 0, 0);
    D[4] = make_uint2(pk_rne(d[0], d[1]), pk_rne(d[2], d[3]));
}

// V-pass for one 16-row out-tile from D_prev (chunk t) + D_cur (chunk t+1).
__device__ __forceinline__ void vstep(const frag& whv,
                                      const uint2* __restrict__ Dp,
                                      const uint2* __restrict__ Dc,
                                      float& lsum)
{
    const f32x4 z = {0.f, 0.f, 0.f, 0.f};
    f32x4 res[5];
#pragma unroll
    for (int p = 0; p < 5; ++p) {
        frag Bf;
        Bf.u[0] = Dp[p].x; Bf.u[1] = Dp[p].y;
        Bf.u[2] = Dc[p].x; Bf.u[3] = Dc[p].y;
        res[p] = __builtin_amdgcn_mfma_f32_16x16x32_bf16(whv.f, Bf.f, z, 0, 0, 0);
    }
#pragma unroll
    for (int j = 0; j < 4; ++j) {
        const float mu1 = res[0][j];
        const float mu2 = res[1][j];
        const float m1s = mu1 * mu1;
        const float m2s = mu2 * mu2;
        const float m12 = mu1 * mu2;
        const float s11 = res[2][j] - m1s;
        const float s22 = res[3][j] - m2s;
        const float s12 = res[4][j] - m12;
        const float num = (2.f * m12 + C1c) * (2.f * s12 + C2c);
        const float den = (m1s + m2s + C1c) * (s11 + s22 + C2c);
        lsum = fmaf(num, __builtin_amdgcn_rcpf(den), lsum);
    }
}

__global__ __launch_bounds__(256, 3)
void ssim_mfma(const float* __restrict__ img1, const float* __restrict__ img2,
               double* __restrict__ acc, unsigned int* __restrict__ cnt,
               float* __restrict__ out)
{
    const int tid  = threadIdx.x;
    const int lane = tid & 63;
    const int wave = tid >> 6;        // 0..3
    const int ln   = lane & 15;
    const int lg   = lane >> 4;       // 0..3

    // ---- XCD-locality decode (bijective, 768 = 8 XCDs x 96 slots).
    const int h    = blockIdx.x;
    const int xcd  = h & 7;
    const int slot = h >> 3;              // 0..95
    const int pr   = xcd * 12 + (slot >> 3);   // 0..95 (by,bz) pair
    const int bx   = slot & 7;
    const int by   = pr & 1;
    const int bz   = pr >> 1;

    const int y0   = by * BY;
    const float* __restrict__ p1 = img1 + (size_t)bz * (IMW * IMH);
    const float* __restrict__ p2 = img2 + (size_t)bz * (IMW * IMH);

    // ---- per-thread weight fragments (bit-identical to old setup kernel):
    //   whf: W[k][n] = wt[k-n-3], k = lg*8+j
    //   whv: W'[k][n] = wt[wr(k)-n-3], wr(k) = (j<4 ? lg*4+j : 12+lg*4+j)
    frag whf, whv;
#pragma unroll
    for (int w = 0; w < 4; ++w) {
        const int ka = lg * 8 + 2 * w;
        whf.u[w] = pk_bf16(wsel(ka - ln - 3), wsel(ka + 1 - ln - 3));
        const int j0  = 2 * w;
        const int wr0 = (j0 < 4) ? (lg * 4 + j0) : (12 + lg * 4 + j0);
        whv.u[w] = pk_bf16(wsel(wr0 - ln - 3), wsel(wr0 + 1 - ln - 3));
    }

    __shared__ __align__(16) char lds[4 * CB];     // 4 chunk buffers
    __shared__ float wsum[4];

    // ---- per-thread load-slot constants (3 groups: L = tid, +256, +512).
    // Lp = L%384; row = Lp/24; slot k = Lp%24 holds seg (k-row)%24 of the
    // window [bx*64-16, +80) (rotate swizzle baked into the SOURCE addr;
    // LDS dest is linear L*16 = wave-uniform base + lane*16 per group).
    const int Lp0 = tid;                       // group0 -> img1
    const int rw0 = Lp0 / 24;
    int sg0 = (Lp0 % 24) - rw0; sg0 += (sg0 < 0) ? 24 : 0;
    int cc0 = bx * TX - 16 + 4 * sg0; cc0 = cc0 < 0 ? 0 : (cc0 > IMW - 4 ? IMW - 4 : cc0);
    const float* gb0 = p1;

    const int L1  = tid + 256;
    const int Lp1 = (L1 < 384) ? L1 : (L1 - 384);
    const int rw1 = Lp1 / 24;
    int sg1 = (Lp1 % 24) - rw1; sg1 += (sg1 < 0) ? 24 : 0;
    int cc1 = bx * TX - 16 + 4 * sg1; cc1 = cc1 < 0 ? 0 : (cc1 > IMW - 4 ? IMW - 4 : cc1);
    const float* gb1 = (L1 < 384) ? p1 : p2;

    const int Lp2 = tid + 512 - 384;           // group2 -> img2
    const int rw2 = Lp2 / 24;
    int sg2 = (Lp2 % 24) - rw2; sg2 += (sg2 < 0) ? 24 : 0;
    int cc2 = bx * TX - 16 + 4 * sg2; cc2 = cc2 < 0 ? 0 : (cc2 > IMW - 4 ? IMW - 4 : cc2);
    const float* gb2 = p2;

    const int wbase = wave * 1024;             // wave-uniform LDS group base

    // ---- fragment read offsets (loop-invariant): row ln, segs s0, s0+1
    const int s0  = 4 * wave + 2 + 2 * lg;
    const int rk0 = (s0 + ln) % 24;
    const int rk1 = (s0 + 1 + ln) % 24;
    const int ro0 = (ln * 24 + rk0) * 16;
    const int ro1 = (ln * 24 + rk1) * 16;
    const int cbase = bx * TX + wave * 16 - 8 + lg * 8;
    const bool colok = ((unsigned)cbase <= (unsigned)(IMW - 8));

    uint2 DA[5], DB[5];
    float lsum = 0.f;

#define CLMP(r) ((r) < 0 ? 0 : ((r) > IMH - 1 ? IMH - 1 : (r)))
#define ISSUE(c, OFF) do{ \
    const int i0 = CLMP(y0 + 16 * (c) - 8 + rw0); \
    const int i1 = CLMP(y0 + 16 * (c) - 8 + rw1); \
    const int i2 = CLMP(y0 + 16 * (c) - 8 + rw2); \
    __builtin_amdgcn_global_load_lds( \
        (const __attribute__((address_space(1))) void*)(gb0 + (size_t)i0 * IMW + cc0), \
        (__attribute__((address_space(3))) void*)(lds + (OFF) + wbase), 16, 0, 0); \
    __builtin_amdgcn_global_load_lds( \
        (const __attribute__((address_space(1))) void*)(gb1 + (size_t)i1 * IMW + cc1), \
        (__attribute__((address_space(3))) void*)(lds + (OFF) + 4096 + wbase), 16, 0, 0); \
    __builtin_amdgcn_global_load_lds( \
        (const __attribute__((address_space(1))) void*)(gb2 + (size_t)i2 * IMW + cc2), \
        (__attribute__((address_space(3))) void*)(lds + (OFF) + 8192 + wbase), 16, 0, 0); \
    } while (0)
#define VMW(n) do{ \
    asm volatile("s_waitcnt vmcnt(" #n ")" ::: "memory"); \
    __builtin_amdgcn_sched_barrier(0); } while (0)
#define BAR() do{ \
    __builtin_amdgcn_sched_barrier(0); \
    __builtin_amdgcn_s_barrier(); \
    __builtin_amdgcn_sched_barrier(0); } while (0)
#define ROWOK(c) (colok && ((unsigned)(y0 + 16 * (c) - 8 + ln) < (unsigned)IMH))

    // ---- prologue: issue chunks 0..2 (9 loads out); wait chunk0; H(0).
    ISSUE(0, 0 * CB);
    ISSUE(1, 1 * CB);
    ISSUE(2, 2 * CB);
    VMW(6);                                // chunk0 writes complete
    BAR();
    cstep<0 * CB>(lds, ro0, ro1, ROWOK(0), whf, DA);   // H of chunk 0

    // ---- main march: step c: ISSUE(c+2 -> buf[(c+2)%4]); vmcnt(6) ->
    // chunk c done, c+1/c+2 in flight across the barrier; cstep(chunk c,
    // buf[c%4]); vstep(tile c-1). Buf reuse separated by step c-1's BAR.
    for (int u = 0; u < 3; ++u) {          // c = 4u+1 .. 4u+4  (1..12)
        const int c0 = 4 * u;
        ISSUE(c0 + 3, 3 * CB); VMW(6); BAR();
        cstep<1 * CB>(lds, ro0, ro1, ROWOK(c0 + 1), whf, DB);
        vstep(whv, DA, DB, lsum);
        ISSUE(c0 + 4, 0 * CB); VMW(6); BAR();
        cstep<2 * CB>(lds, ro0, ro1, ROWOK(c0 + 2), whf, DA);
        vstep(whv, DB, DA, lsum);
        ISSUE(c0 + 5, 1 * CB); VMW(6); BAR();
        cstep<3 * CB>(lds, ro0, ro1, ROWOK(c0 + 3), whf, DB);
        vstep(whv, DA, DB, lsum);
        ISSUE(c0 + 6, 2 * CB); VMW(6); BAR();
        cstep<0 * CB>(lds, ro0, ro1, ROWOK(c0 + 4), whf, DA);
        vstep(whv, DB, DA, lsum);
    }
    // c = 13
    ISSUE(15, 3 * CB); VMW(6); BAR();
    cstep<1 * CB>(lds, ro0, ro1, ROWOK(13), whf, DB);
    vstep(whv, DA, DB, lsum);
    // c = 14
    ISSUE(16, 0 * CB); VMW(6); BAR();
    cstep<2 * CB>(lds, ro0, ro1, ROWOK(14), whf, DA);
    vstep(whv, DB, DA, lsum);
    // c = 15 (no issue; chunk16's 3 loads outstanding)
    VMW(3); BAR();
    cstep<3 * CB>(lds, ro0, ro1, ROWOK(15), whf, DB);
    vstep(whv, DA, DB, lsum);
    // c = 16
    VMW(0); BAR();
    cstep<0 * CB>(lds, ro0, ro1, ROWOK(16), whf, DA);
    vstep(whv, DB, DA, lsum);
#undef CLMP
#undef ISSUE
#undef VMW
#undef BAR
#undef ROWOK

    // ---- Block reduction -> device-scope atomic accumulate; the last
    // block to finish computes and writes the final scalar.
#pragma unroll
    for (int off = 32; off > 0; off >>= 1)
        lsum += __shfl_down(lsum, off, 64);

    if (lane == 0) wsum[wave] = lsum;
    __syncthreads();
    if (tid == 0) {
        float tot = wsum[0] + wsum[1] + wsum[2] + wsum[3];
        atomicAdd(acc, (double)tot);
        __threadfence();
        unsigned int old = atomicAdd(cnt, 1u);
        if (old == (unsigned int)(NBLK - 1)) {
            double sum = atomicAdd(acc, 0.0);      // atomic read
            double mean = sum / (double)((size_t)NPL * IMW * IMH);
            out[0] = (float)(1.0 - mean);
        }
    }
}

extern "C" void kernel_launch(void* const* d_in, const int* in_sizes, int n_in,
                              void* d_out, int out_size, void* d_ws, size_t ws_size,
                              hipStream_t stream)
{
    (void)in_sizes; (void)n_in; (void)out_size; (void)ws_size;
    const float* img1 = (const float*)d_in[0];
    const float* img2 = (const float*)d_in[1];
    float* out = (float*)d_out;

    double* acc = (double*)d_ws;                       // [0,8): sum
    unsigned int* cnt = (unsigned int*)((char*)d_ws + 8);  // [8,12): counter

    hipMemsetAsync(d_ws, 0, 16, stream);
    ssim_mfma<<<dim3(NBLK), 256, 0, stream>>>(img1, img2, acc, cnt, out);
}

// Round 20
// 29.399 us; speedup vs baseline: 1.6956x; 1.6956x over previous
//
#include <hip/hip_runtime.h>

// SSIM v32: v29 EXACT main loop + reduce kernel (33.3us best), with only
// the weight-setup dispatch folded into the main kernel prologue.
// v31's full fusion regressed (+16.5us): the 768-block single-cacheline
// atomic tail (1536 device RMWs + 768 threadfences, all arriving at
// once) cost ~20us -- Guideline 12 violation. The in-kernel weight
// compute itself is innocuous (~200 VALU once, VGPR unchanged at 80).
// v32 keeps the partials-array + tiny-reduce structure (no atomics) and
// saves one dispatch+gap (~1.5-2.5us). pk_bf16 software RNE produces
// bit-identical weight words to the old setup kernel -> absmax exactly
// 0.0078125.

typedef __attribute__((ext_vector_type(8))) short bf16x8;
typedef __attribute__((ext_vector_type(4))) float f32x4;
typedef __attribute__((ext_vector_type(2))) float f32x2;
typedef __attribute__((ext_vector_type(2))) __bf16 bfx2;

constexpr int TX   = 64;             // block out-cols (4 waves x 16)
constexpr int BY   = 256;            // block out-rows
constexpr int IMW  = 512;
constexpr int IMH  = 512;
constexpr int NPL  = 48;
constexpr int GX   = IMW / TX;       // 8
constexpr int GYB  = IMH / BY;       // 2
constexpr int NBLK = GX * GYB * NPL; // 768
constexpr int NCH  = BY / 16;        // 16; chunks 0..16
constexpr int CB   = 12288;          // bytes per chunk buffer (768 float4)
constexpr float C1c = 0.01f * 0.01f;
constexpr float C2c = 0.03f * 0.03f;

union frag {
    bf16x8 f;
    unsigned int u[4];
    uint4 q;
};

// RNE f32->bf16 pair pack, software (weight init; bit-identical to HW RNE).
__device__ __forceinline__ unsigned int pk_bf16(float lo, float hi) {
    unsigned int a = __float_as_uint(lo);
    unsigned int b = __float_as_uint(hi);
    a += 0x7FFFu + ((a >> 16) & 1u);
    b += 0x7FFFu + ((b >> 16) & 1u);
    return (b & 0xFFFF0000u) | (a >> 16);
}

// HW RNE pair pack: vector fptrunc -> v_cvt_pk_bf16_f32 (1 VALU op).
__device__ __forceinline__ unsigned int pk_rne(float lo, float hi) {
    f32x2 v; v.x = lo; v.y = hi;
    bfx2 b = __builtin_convertvector(v, bfx2);
    return *reinterpret_cast<unsigned int*>(&b);
}

// Normalized 11-tap Gaussian (sigma=1.5); wt[d] for d in [0,11), else 0.
__device__ __forceinline__ float wsel(int d) {
    float w = 0.f;
    w = (d == 0 || d == 10) ? 0.00102838f : w;
    w = (d == 1 || d == 9)  ? 0.00759876f : w;
    w = (d == 2 || d == 8)  ? 0.03600077f : w;
    w = (d == 3 || d == 7)  ? 0.10936082f : w;
    w = (d == 4 || d == 6)  ? 0.21300553f : w;
    w = (d == 5)            ? 0.26601171f : w;
    return w;
}

// H-pass for one chunk from LDS: read 2 f4/img (= v12's 8 fragment floats),
// zero-predicate, pack (RNE cvt_pk), 5 MFMAs -> packed D (uint2 per plane).
template<int OFF>
__device__ __forceinline__ void cstep(const char* lds, int ro0, int ro1, bool ok,
                                      const frag& whf,
                                      uint2* __restrict__ D)
{
    float4 ra0 = *reinterpret_cast<const float4*>(lds + OFF + ro0);
    float4 ra1 = *reinterpret_cast<const float4*>(lds + OFF + ro1);
    float4 rb0 = *reinterpret_cast<const float4*>(lds + OFF + CB / 2 + ro0);
    float4 rb1 = *reinterpret_cast<const float4*>(lds + OFF + CB / 2 + ro1);
    const float4 zz = make_float4(0.f, 0.f, 0.f, 0.f);
    if (!ok) { ra0 = zz; ra1 = zz; rb0 = zz; rb1 = zz; }

    const f32x4 z = {0.f, 0.f, 0.f, 0.f};
    frag fa, fb, faa, fbb, fab;
    fa.u[0]  = pk_rne(ra0.x, ra0.y);               fb.u[0]  = pk_rne(rb0.x, rb0.y);
    faa.u[0] = pk_rne(ra0.x*ra0.x, ra0.y*ra0.y);
    fbb.u[0] = pk_rne(rb0.x*rb0.x, rb0.y*rb0.y);
    fab.u[0] = pk_rne(ra0.x*rb0.x, ra0.y*rb0.y);
    fa.u[1]  = pk_rne(ra0.z, ra0.w);               fb.u[1]  = pk_rne(rb0.z, rb0.w);
    faa.u[1] = pk_rne(ra0.z*ra0.z, ra0.w*ra0.w);
    fbb.u[1] = pk_rne(rb0.z*rb0.z, rb0.w*rb0.w);
    fab.u[1] = pk_rne(ra0.z*rb0.z, ra0.w*rb0.w);
    fa.u[2]  = pk_rne(ra1.x, ra1.y);               fb.u[2]  = pk_rne(rb1.x, rb1.y);
    faa.u[2] = pk_rne(ra1.x*ra1.x, ra1.y*ra1.y);
    fbb.u[2] = pk_rne(rb1.x*rb1.x, rb1.y*rb1.y);
    fab.u[2] = pk_rne(ra1.x*rb1.x, ra1.y*rb1.y);
    fa.u[3]  = pk_rne(ra1.z, ra1.w);               fb.u[3]  = pk_rne(rb1.z, rb1.w);
    faa.u[3] = pk_rne(ra1.z*ra1.z, ra1.w*ra1.w);
    fbb.u[3] = pk_rne(rb1.z*rb1.z, rb1.w*rb1.w);
    fab.u[3] = pk_rne(ra1.z*rb1.z, ra1.w*rb1.w);

    f32x4 d;
    d = __builtin_amdgcn_mfma_f32_16x16x32_bf16(fa.f,  whf.f, z, 0, 0, 0);
    D[0] = make_uint2(pk_rne(d[0], d[1]), pk_rne(d[2], d[3]));
    d = __builtin_amdgcn_mfma_f32_16x16x32_bf16(fb.f,  whf.f, z, 0, 0, 0);
    D[1] = make_uint2(pk_rne(d[0], d[1]), pk_rne(d[2], d[3]));
    d = __builtin_amdgcn_mfma_f32_16x16x32_bf16(faa.f, whf.f, z, 0, 0, 0);
    D[2] = make_uint2(pk_rne(d[0], d[1]), pk_rne(d[2], d[3]));
    d = __builtin_amdgcn_mfma_f32_16x16x32_bf16(fbb.f, whf.f, z, 0, 0, 0);
    D[3] = make_uint2(pk_rne(d[0], d[1]), pk_rne(d[2], d[3]));
    d = __builtin_amdgcn_mfma_f32_16x16x32_bf16(fab.f, whf.f, z, 0, 0, 0);
    D[4] = make_uint2(pk_rne(d[0], d[1]), pk_rne(d[2], d[3]));
}

// V-pass for one 16-row out-tile from D_prev (chunk t) + D_cur (chunk t+1).
__device__ __forceinline__ void vstep(const frag& whv,
                                      const uint2* __restrict__ Dp,
                                      const uint2* __restrict__ Dc,
                                      float& lsum)
{
    const f32x4 z = {0.f, 0.f, 0.f, 0.f};
    f32x4 res[5];
#pragma unroll
    for (int p = 0; p < 5; ++p) {
        frag Bf;
        Bf.u[0] = Dp[p].x; Bf.u[1] = Dp[p].y;
        Bf.u[2] = Dc[p].x; Bf.u[3] = Dc[p].y;
        res[p] = __builtin_amdgcn_mfma_f32_16x16x32_bf16(whv.f, Bf.f, z, 0, 0, 0);
    }
#pragma unroll
    for (int j = 0; j < 4; ++j) {
        const float mu1 = res[0][j];
        const float mu2 = res[1][j];
        const float m1s = mu1 * mu1;
        const float m2s = mu2 * mu2;
        const float m12 = mu1 * mu2;
        const float s11 = res[2][j] - m1s;
        const float s22 = res[3][j] - m2s;
        const float s12 = res[4][j] - m12;
        const float num = (2.f * m12 + C1c) * (2.f * s12 + C2c);
        const float den = (m1s + m2s + C1c) * (s11 + s22 + C2c);
        lsum = fmaf(num, __builtin_amdgcn_rcpf(den), lsum);
    }
}

__global__ __launch_bounds__(256, 3)
void ssim_mfma(const float* __restrict__ img1, const float* __restrict__ img2,
               float* __restrict__ partials)
{
    const int tid  = threadIdx.x;
    const int lane = tid & 63;
    const int wave = tid >> 6;        // 0..3
    const int ln   = lane & 15;
    const int lg   = lane >> 4;       // 0..3

    // ---- XCD-locality decode (bijective, 768 = 8 XCDs x 96 slots).
    const int h    = blockIdx.x;
    const int xcd  = h & 7;
    const int slot = h >> 3;              // 0..95
    const int pr   = xcd * 12 + (slot >> 3);   // 0..95 (by,bz) pair
    const int bx   = slot & 7;
    const int by   = pr & 1;
    const int bz   = pr >> 1;

    const int y0   = by * BY;
    const float* __restrict__ p1 = img1 + (size_t)bz * (IMW * IMH);
    const float* __restrict__ p2 = img2 + (size_t)bz * (IMW * IMH);

    // ---- per-thread weight fragments (bit-identical to old setup kernel):
    //   whf: W[k][n] = wt[k-n-3], k = lg*8+j
    //   whv: W'[k][n] = wt[wr(k)-n-3], wr(k) = (j<4 ? lg*4+j : 12+lg*4+j)
    frag whf, whv;
#pragma unroll
    for (int w = 0; w < 4; ++w) {
        const int ka = lg * 8 + 2 * w;
        whf.u[w] = pk_bf16(wsel(ka - ln - 3), wsel(ka + 1 - ln - 3));
        const int j0  = 2 * w;
        const int wr0 = (j0 < 4) ? (lg * 4 + j0) : (12 + lg * 4 + j0);
        whv.u[w] = pk_bf16(wsel(wr0 - ln - 3), wsel(wr0 + 1 - ln - 3));
    }

    __shared__ __align__(16) char lds[4 * CB];     // 4 chunk buffers
    __shared__ float wsum[4];

    // ---- per-thread load-slot constants (3 groups: L = tid, +256, +512).
    // Lp = L%384; row = Lp/24; slot k = Lp%24 holds seg (k-row)%24 of the
    // window [bx*64-16, +80) (rotate swizzle baked into the SOURCE addr;
    // LDS dest is linear L*16 = wave-uniform base + lane*16 per group).
    const int Lp0 = tid;                       // group0 -> img1
    const int rw0 = Lp0 / 24;
    int sg0 = (Lp0 % 24) - rw0; sg0 += (sg0 < 0) ? 24 : 0;
    int cc0 = bx * TX - 16 + 4 * sg0; cc0 = cc0 < 0 ? 0 : (cc0 > IMW - 4 ? IMW - 4 : cc0);
    const float* gb0 = p1;

    const int L1  = tid + 256;
    const int Lp1 = (L1 < 384) ? L1 : (L1 - 384);
    const int rw1 = Lp1 / 24;
    int sg1 = (Lp1 % 24) - rw1; sg1 += (sg1 < 0) ? 24 : 0;
    int cc1 = bx * TX - 16 + 4 * sg1; cc1 = cc1 < 0 ? 0 : (cc1 > IMW - 4 ? IMW - 4 : cc1);
    const float* gb1 = (L1 < 384) ? p1 : p2;

    const int Lp2 = tid + 512 - 384;           // group2 -> img2
    const int rw2 = Lp2 / 24;
    int sg2 = (Lp2 % 24) - rw2; sg2 += (sg2 < 0) ? 24 : 0;
    int cc2 = bx * TX - 16 + 4 * sg2; cc2 = cc2 < 0 ? 0 : (cc2 > IMW - 4 ? IMW - 4 : cc2);
    const float* gb2 = p2;

    const int wbase = wave * 1024;             // wave-uniform LDS group base

    // ---- fragment read offsets (loop-invariant): row ln, segs s0, s0+1
    const int s0  = 4 * wave + 2 + 2 * lg;
    const int rk0 = (s0 + ln) % 24;
    const int rk1 = (s0 + 1 + ln) % 24;
    const int ro0 = (ln * 24 + rk0) * 16;
    const int ro1 = (ln * 24 + rk1) * 16;
    const int cbase = bx * TX + wave * 16 - 8 + lg * 8;
    const bool colok = ((unsigned)cbase <= (unsigned)(IMW - 8));

    uint2 DA[5], DB[5];
    float lsum = 0.f;

#define CLMP(r) ((r) < 0 ? 0 : ((r) > IMH - 1 ? IMH - 1 : (r)))
#define ISSUE(c, OFF) do{ \
    const int i0 = CLMP(y0 + 16 * (c) - 8 + rw0); \
    const int i1 = CLMP(y0 + 16 * (c) - 8 + rw1); \
    const int i2 = CLMP(y0 + 16 * (c) - 8 + rw2); \
    __builtin_amdgcn_global_load_lds( \
        (const __attribute__((address_space(1))) void*)(gb0 + (size_t)i0 * IMW + cc0), \
        (__attribute__((address_space(3))) void*)(lds + (OFF) + wbase), 16, 0, 0); \
    __builtin_amdgcn_global_load_lds( \
        (const __attribute__((address_space(1))) void*)(gb1 + (size_t)i1 * IMW + cc1), \
        (__attribute__((address_space(3))) void*)(lds + (OFF) + 4096 + wbase), 16, 0, 0); \
    __builtin_amdgcn_global_load_lds( \
        (const __attribute__((address_space(1))) void*)(gb2 + (size_t)i2 * IMW + cc2), \
        (__attribute__((address_space(3))) void*)(lds + (OFF) + 8192 + wbase), 16, 0, 0); \
    } while (0)
#define VMW(n) do{ \
    asm volatile("s_waitcnt vmcnt(" #n ")" ::: "memory"); \
    __builtin_amdgcn_sched_barrier(0); } while (0)
#define BAR() do{ \
    __builtin_amdgcn_sched_barrier(0); \
    __builtin_amdgcn_s_barrier(); \
    __builtin_amdgcn_sched_barrier(0); } while (0)
#define ROWOK(c) (colok && ((unsigned)(y0 + 16 * (c) - 8 + ln) < (unsigned)IMH))

    // ---- prologue: issue chunks 0..2 (9 loads out); wait chunk0; H(0).
    ISSUE(0, 0 * CB);
    ISSUE(1, 1 * CB);
    ISSUE(2, 2 * CB);
    VMW(6);                                // chunk0 writes complete
    BAR();
    cstep<0 * CB>(lds, ro0, ro1, ROWOK(0), whf, DA);   // H of chunk 0

    // ---- main march: step c: ISSUE(c+2 -> buf[(c+2)%4]); vmcnt(6) ->
    // chunk c done, c+1/c+2 in flight across the barrier; cstep(chunk c,
    // buf[c%4]); vstep(tile c-1). Buf reuse separated by step c-1's BAR.
    for (int u = 0; u < 3; ++u) {          // c = 4u+1 .. 4u+4  (1..12)
        const int c0 = 4 * u;
        ISSUE(c0 + 3, 3 * CB); VMW(6); BAR();
        cstep<1 * CB>(lds, ro0, ro1, ROWOK(c0 + 1), whf, DB);
        vstep(whv, DA, DB, lsum);
        ISSUE(c0 + 4, 0 * CB); VMW(6); BAR();
        cstep<2 * CB>(lds, ro0, ro1, ROWOK(c0 + 2), whf, DA);
        vstep(whv, DB, DA, lsum);
        ISSUE(c0 + 5, 1 * CB); VMW(6); BAR();
        cstep<3 * CB>(lds, ro0, ro1, ROWOK(c0 + 3), whf, DB);
        vstep(whv, DA, DB, lsum);
        ISSUE(c0 + 6, 2 * CB); VMW(6); BAR();
        cstep<0 * CB>(lds, ro0, ro1, ROWOK(c0 + 4), whf, DA);
        vstep(whv, DB, DA, lsum);
    }
    // c = 13
    ISSUE(15, 3 * CB); VMW(6); BAR();
    cstep<1 * CB>(lds, ro0, ro1, ROWOK(13), whf, DB);
    vstep(whv, DA, DB, lsum);
    // c = 14
    ISSUE(16, 0 * CB); VMW(6); BAR();
    cstep<2 * CB>(lds, ro0, ro1, ROWOK(14), whf, DA);
    vstep(whv, DB, DA, lsum);
    // c = 15 (no issue; chunk16's 3 loads outstanding)
    VMW(3); BAR();
    cstep<3 * CB>(lds, ro0, ro1, ROWOK(15), whf, DB);
    vstep(whv, DA, DB, lsum);
    // c = 16
    VMW(0); BAR();
    cstep<0 * CB>(lds, ro0, ro1, ROWOK(16), whf, DA);
    vstep(whv, DB, DA, lsum);
#undef CLMP
#undef ISSUE
#undef VMW
#undef BAR
#undef ROWOK

    // ---- Block reduction -> per-block partial ----
#pragma unroll
    for (int off = 32; off > 0; off >>= 1)
        lsum += __shfl_down(lsum, off, 64);

    if (lane == 0) wsum[wave] = lsum;
    __syncthreads();
    if (tid == 0) {
        float tot = wsum[0] + wsum[1] + wsum[2] + wsum[3];
        const int bid = (bz * GYB + by) * GX + bx;
        partials[bid] = tot;
    }
}

__global__ __launch_bounds__(256)
void ssim_reduce_kernel(const float* __restrict__ partials,
                        float* __restrict__ out)
{
    __shared__ double sm[256];
    double s = 0.0;
    for (int i = threadIdx.x; i < NBLK; i += 256) s += (double)partials[i];
    sm[threadIdx.x] = s;
    __syncthreads();
    for (int stride = 128; stride > 0; stride >>= 1) {
        if (threadIdx.x < stride) sm[threadIdx.x] += sm[threadIdx.x + stride];
        __syncthreads();
    }
    if (threadIdx.x == 0) {
        double mean = sm[0] / (double)((size_t)NPL * IMW * IMH);
        out[0] = (float)(1.0 - mean);
    }
}

extern "C" void kernel_launch(void* const* d_in, const int* in_sizes, int n_in,
                              void* d_out, int out_size, void* d_ws, size_t ws_size,
                              hipStream_t stream)
{
    (void)in_sizes; (void)n_in; (void)out_size; (void)ws_size;
    const float* img1 = (const float*)d_in[0];
    const float* img2 = (const float*)d_in[1];
    float* out = (float*)d_out;

    float* partials = (float*)((char*)d_ws + 4096);        // NBLK floats

    ssim_mfma<<<dim3(NBLK), 256, 0, stream>>>(img1, img2, partials);
    ssim_reduce_kernel<<<1, 256, 0, stream>>>(partials, out);
}